// Round 4
// baseline (1023.600 us; speedup 1.0000x reference)
//
#include <hip/hip_runtime.h>
#include <stdint.h>

// GraphLayer: B=16384, F=50, E=64, all fp32.
//   h_out[b,f,i] = sum_j W_out[f,i,j] * h[b,f,j]
//   aggr[b,f,e]  = sum_g g[b,f,g] * h_out[b,g,e]
//   a[b,f,i]     = sum_j W_in[f,i,j] * aggr[b,f,j] + bias[i]
//
// Round 6: resubmit of round-5 source (bench infra failed twice; kernel
// audited for OOB/hang -- clean).  Rationale unchanged:
// Both kernels were latency-bound with LDS CAPACITY as the occupancy
// limiter (field_gemm 80 KB -> 2 blk/CU = 8 waves; aggr 47 KB -> 3 blk/CU
// = 6 waves).  Evict from LDS everything whose reuse the caches serve:
//   * field_gemm: W read straight from L1/L2 (wave-dedup'd 128 B/inst; only
//     16 KB/wave of L2 traffic).  LDS = h tile only, BT=128 -> 32 KB/block,
//     5 blocks/CU = 10 waves (2.5/SIMD).  LDS-pipe per jq halves (8 b128
//     instead of 16) -> kernel becomes VALU-bound (floor ~43 us).
//   * aggr: g reads are 8-way same-address broadcasts -> global coalescer
//     dedups them; g[b] (10 KB) walks sequentially through L1.  LDS = ho
//     only (25.6 KB/block, no pad rows) -> 6 blocks/CU = 12 waves (3/SIMD).
//     Staging via per-wave global_load_lds + vmcnt(0): NO barrier (each
//     wave owns its batch).  Explicit g0=48 tail (no pad rows, no OOB).

static constexpr int Bz  = 16384;
static constexpr int Ff  = 50;
static constexpr int Ee  = 64;
static constexpr int BT  = 128;   // batch tile for per-field GEMM

__device__ __forceinline__ void fma4(float4& a, float s, const float4& v) {
    a.x += s * v.x; a.y += s * v.y; a.z += s * v.z; a.w += s * v.w;
}

// async global->LDS, 16 B per lane.  HW semantics: LDS dest = wave-uniform
// base + laneid*16; our dests are linear in lane id, consistent with that.
__device__ __forceinline__ void gld_lds16(const float* gsrc, float* ldst) {
    __builtin_amdgcn_global_load_lds(
        (const __attribute__((address_space(1))) uint32_t*)gsrc,
        (__attribute__((address_space(3))) uint32_t*)ldst, 16, 0, 0);
}

// dst[b,f,i] = sum_j W[f,i,j]*src[b,f,j] (+ bias[i]).  In-place (src==dst)
// safe: all global reads of src land in LDS before the barrier; stores after;
// each (b,f,:) row is owned by exactly one block.
// LDS layout (h only): f4-slot (row r, chunk c) holds global chunk
// (r, c ^ (r&7)); compute reads slot (row, jq ^ (row&7)) -> global (row, jq).
// Per b128 read the wave's 8 distinct rows are distinct mod 8 -> XOR spreads
// across all 32 banks (8-way broadcast per address): conflict-free.
__global__ __launch_bounds__(128, 2)
void field_gemm(const float* __restrict__ src, float* __restrict__ dst,
                const float* __restrict__ W, const float* __restrict__ bias) {
    __shared__ __attribute__((aligned(16))) float h_lds[BT * Ee];  // 32 KB
    const int f  = blockIdx.y;
    const int b0 = blockIdx.x * BT;
    const int t  = threadIdx.x;

    // stage src tile: 2048 float4 (16 per thread), linear LDS, swizzled src
    const float4* s4 = (const float4*)src;
#pragma unroll
    for (int k = 0; k < 16; ++k) {
        int q = k * 128 + t;
        int r = q >> 4, c = q & 15;
        gld_lds16((const float*)&s4[(size_t)(b0 + r) * (Ff * Ee / 4) + f * 16 + (c ^ (r & 7))],
                  &h_lds[q * 4]);
    }
    __syncthreads();   // cross-wave tile use -> barrier (drains vmcnt)

    const int ti  = t & 7;    // i  = ti + 8*ii;  row&7 distinct per lane
    const int tb  = t >> 3;   // bb = tb + 16*kb; (tb in 0..15)
    const int tb7 = tb & 7;
    const float4* hp = (const float4*)h_lds;
    const float4* Wf = (const float4*)(W + (size_t)f * (Ee * Ee));  // [64][16]

    float acc[8][8];
#pragma unroll
    for (int ii = 0; ii < 8; ++ii)
#pragma unroll
        for (int kb = 0; kb < 8; ++kb) acc[ii][kb] = 0.f;

#pragma unroll 2
    for (int jq = 0; jq < 16; ++jq) {          // j = 4*jq .. 4*jq+3
        float4 w4[8], h4[8];
#pragma unroll
        for (int ii = 0; ii < 8; ++ii)         // global: L1-resident W[f]
            w4[ii] = Wf[(ti + 8 * ii) * 16 + jq];
#pragma unroll
        for (int kb = 0; kb < 8; ++kb)
            h4[kb] = hp[(tb + 16 * kb) * 16 + (jq ^ tb7)];
#pragma unroll
        for (int ii = 0; ii < 8; ++ii)
#pragma unroll
            for (int kb = 0; kb < 8; ++kb) {
                acc[ii][kb] += w4[ii].x * h4[kb].x;
                acc[ii][kb] += w4[ii].y * h4[kb].y;
                acc[ii][kb] += w4[ii].z * h4[kb].z;
                acc[ii][kb] += w4[ii].w * h4[kb].w;
            }
    }

    // stores: per inst, wave covers 8 rows x 32 B contiguous; consecutive ii
    // fill neighboring 32 B of the same rows -> L2 write-combines (WRITE_SIZE
    // measured ideal in rounds 1-2).
#pragma unroll
    for (int ii = 0; ii < 8; ++ii) {
        const int i  = ti + 8 * ii;
        const float bv = bias ? bias[i] : 0.0f;
#pragma unroll
        for (int kb = 0; kb < 8; ++kb) {
            const int bb = tb + 16 * kb;
            dst[(size_t)(b0 + bb) * (Ff * Ee) + f * Ee + i] = acc[ii][kb] + bv;
        }
    }
}

// aggr[b,f,e] = sum_g g[b,f,g] * ho[b,g,e], in place over ho (d_out).
// 128 threads = 2 waves; each wave owns one batch with its own LDS region --
// no __syncthreads anywhere (per-wave vmcnt(0) fence instead).
// LDS: ho[b] only (800 f4 = 12.8 KB/batch, linear; reads are 2-way bank
// aliased = free).  g read from global: 8-way same-address broadcast per
// inst, g[b]=10 KB walks L1 sequentially.
static constexpr int HOQ = (Ff * Ee) / 4;   // 800 f4 per batch

__global__ __launch_bounds__(128, 3)
void aggr_inplace(const float* __restrict__ g, float* __restrict__ ho) {
    __shared__ __attribute__((aligned(16))) float lds[2 * HOQ * 4];  // 25.6 KB
    const int t    = threadIdx.x;
    const int wid  = t >> 6;
    const int lane = t & 63;
    const int b    = blockIdx.x * 2 + wid;
    float* ho_sh = &lds[wid * (HOQ * 4)];

    const float4* hosrc = (const float4*)(ho + (size_t)b * (Ff * Ee));
#pragma unroll
    for (int k = 0; k < 12; ++k) {            // 768 f4
        int q = k * 64 + lane;
        gld_lds16((const float*)&hosrc[q], &ho_sh[q * 4]);
    }
    if (lane < 32)                            // last 32 f4 (exec-masked)
        gld_lds16((const float*)&hosrc[768 + lane], &ho_sh[(768 + lane) * 4]);

    // own-wave loads only -> waitcnt, no barrier.  sched_barrier keeps the
    // compiler from hoisting the dependent ds_reads above the wait.
    asm volatile("s_waitcnt vmcnt(0)" ::: "memory");
    __builtin_amdgcn_sched_barrier(0);

    const float* gb = g + (size_t)b * (Ff * Ff);
    const int te = lane & 7;
    const int tf = lane >> 3;
    const int e0 = te * 8;
    float4 acc[7][2];
#pragma unroll
    for (int k = 0; k < 7; ++k) {
        acc[k][0] = make_float4(0.f, 0.f, 0.f, 0.f);
        acc[k][1] = make_float4(0.f, 0.f, 0.f, 0.f);
    }

#pragma unroll 2
    for (int g0 = 0; g0 < 48; g0 += 4) {
        float4 ho4[4][2];
#pragma unroll
        for (int q = 0; q < 4; ++q) {
            ho4[q][0] = *(const float4*)&ho_sh[(g0 + q) * Ee + e0];
            ho4[q][1] = *(const float4*)&ho_sh[(g0 + q) * Ee + e0 + 4];
        }
#pragma unroll
        for (int k = 0; k < 7; ++k) {
            int fi = tf * 7 + k;
            fi = (fi < Ff) ? fi : (Ff - 1);   // clamp; duplicates not stored
            const float2 ga = *(const float2*)&gb[fi * Ff + g0];
            const float2 gc = *(const float2*)&gb[fi * Ff + g0 + 2];
            fma4(acc[k][0], ga.x, ho4[0][0]); fma4(acc[k][1], ga.x, ho4[0][1]);
            fma4(acc[k][0], ga.y, ho4[1][0]); fma4(acc[k][1], ga.y, ho4[1][1]);
            fma4(acc[k][0], gc.x, ho4[2][0]); fma4(acc[k][1], gc.x, ho4[2][1]);
            fma4(acc[k][0], gc.y, ho4[3][0]); fma4(acc[k][1], gc.y, ho4[3][1]);
        }
    }
    {   // tail: g0 = 48,49 (no pad rows, no OOB)
        float4 ho4[2][2];
        ho4[0][0] = *(const float4*)&ho_sh[48 * Ee + e0];
        ho4[0][1] = *(const float4*)&ho_sh[48 * Ee + e0 + 4];
        ho4[1][0] = *(const float4*)&ho_sh[49 * Ee + e0];
        ho4[1][1] = *(const float4*)&ho_sh[49 * Ee + e0 + 4];
#pragma unroll
        for (int k = 0; k < 7; ++k) {
            int fi = tf * 7 + k;
            fi = (fi < Ff) ? fi : (Ff - 1);
            const float2 ga = *(const float2*)&gb[fi * Ff + 48];
            fma4(acc[k][0], ga.x, ho4[0][0]); fma4(acc[k][1], ga.x, ho4[0][1]);
            fma4(acc[k][0], ga.y, ho4[1][0]); fma4(acc[k][1], ga.y, ho4[1][1]);
        }
    }

    float* hb = ho + (size_t)b * (Ff * Ee);
#pragma unroll
    for (int k = 0; k < 7; ++k) {
        const int fi = tf * 7 + k;          // unclamped for the store guard
        if (fi < Ff) {
            *(float4*)&hb[fi * Ee + e0]     = acc[k][0];
            *(float4*)&hb[fi * Ee + e0 + 4] = acc[k][1];
        }
    }
}

extern "C" void kernel_launch(void* const* d_in, const int* in_sizes, int n_in,
                              void* d_out, int out_size, void* d_ws, size_t ws_size,
                              hipStream_t stream) {
    const float* g     = (const float*)d_in[0];
    const float* h     = (const float*)d_in[1];
    const float* W_in  = (const float*)d_in[2];
    const float* W_out = (const float*)d_in[3];
    const float* bias  = (const float*)d_in[4];
    float* out = (float*)d_out;

    dim3 grid1(Bz / BT, Ff);   // (128, 50)
    // stage 1: h_out -> d_out
    field_gemm<<<grid1, 128, 0, stream>>>(h, out, W_out, nullptr);
    // stage 2: aggr, in place over d_out (one wave per batch)
    aggr_inplace<<<Bz / 2, 128, 0, stream>>>(g, out);
    // stage 3: a = W_in * aggr + bias, in place over d_out
    field_gemm<<<grid1, 128, 0, stream>>>(out, out, W_in, bias);
}